// Round 1
// baseline (240.264 us; speedup 1.0000x reference)
//
#include <hip/hip_runtime.h>

typedef __attribute__((ext_vector_type(8))) _Float16 f16x8;
typedef __attribute__((ext_vector_type(4))) float f32x4;

#define BHn 64
#define Nn 1024

static constexpr int kOutMvElems = 8 * 8 * 1024 * 128;      // 8388608
static constexpr float kScaleLog2e = 0.11405506f;           // log2(e)/sqrt(160)
static constexpr unsigned kNegMask = 0xBF1Cu;               // BLADE_METRIC<0 bit i

// ---------------- pack K: f32 (mv|s) -> f16 [bh][key][160] ----------------
__global__ __launch_bounds__(256) void pack_k_kernel(const float* __restrict__ kmv,
                                                     const float* __restrict__ ks,
                                                     _Float16* __restrict__ Kf) {
  int t = blockIdx.x * 256 + threadIdx.x;  // 16B segment id
  const int total = BHn * Nn * 20;
  if (t >= total) return;
  int row = t / 20, s = t - row * 20;
  const float* src = (s < 16) ? (kmv + (size_t)row * 128 + s * 8)
                              : (ks + (size_t)row * 32 + (s - 16) * 8);
  float4 a = *(const float4*)src;
  float4 b = *(const float4*)(src + 4);
  f16x8 h;
  h[0] = (_Float16)a.x; h[1] = (_Float16)a.y; h[2] = (_Float16)a.z; h[3] = (_Float16)a.w;
  h[4] = (_Float16)b.x; h[5] = (_Float16)b.y; h[6] = (_Float16)b.z; h[7] = (_Float16)b.w;
  *(f16x8*)(Kf + (size_t)row * 160 + s * 8) = h;
}

// ---------------- pack V transposed: f32 [bh][key][160] -> f16 [bh][d][1024] ----------------
__global__ __launch_bounds__(256) void pack_vt_kernel(const float* __restrict__ vmv,
                                                      const float* __restrict__ vs,
                                                      _Float16* __restrict__ Vt) {
  __shared__ _Float16 tile[160][72];
  const int bh = blockIdx.y;
  const int kt = blockIdx.x;  // 16 tiles of 64 keys
  const int tid = threadIdx.x;
  for (int s = tid; s < 64 * 40; s += 256) {
    int key = s / 40, p = s - key * 40;
    int row = bh * Nn + kt * 64 + key;
    const float* src = (p < 32) ? (vmv + (size_t)row * 128 + p * 4)
                                : (vs + (size_t)row * 32 + (p - 32) * 4);
    float4 v = *(const float4*)src;
    int d = p * 4;
    tile[d + 0][key] = (_Float16)v.x;
    tile[d + 1][key] = (_Float16)v.y;
    tile[d + 2][key] = (_Float16)v.z;
    tile[d + 3][key] = (_Float16)v.w;
  }
  __syncthreads();
  for (int s = tid; s < 160 * 8; s += 256) {
    int d = s >> 3, p = s & 7;
    f16x8 h = *(const f16x8*)&tile[d][p * 8];
    *(f16x8*)(Vt + ((size_t)(bh * 160 + d)) * 1024 + kt * 64 + p * 8) = h;
  }
}

// ---------------- flash attention ----------------
// grid (16 qblocks, 64 bh), 256 threads = 4 waves; wave owns 16 Q rows.
__global__ __launch_bounds__(256) void geo_attn_kernel(const float* __restrict__ qmv,
                                                       const float* __restrict__ qs,
                                                       const _Float16* __restrict__ Kf,
                                                       const _Float16* __restrict__ Vt,
                                                       float* __restrict__ out) {
  __shared__ _Float16 k_lds[32 * 168];   // 32 keys x 160 (+8 pad)
  __shared__ _Float16 v_lds[160 * 40];   // 160 d x 32 keys (+8 pad)
  __shared__ _Float16 p_lds[4 * 16 * 40];  // per-wave P scratch

  const int bh = blockIdx.y;
  const int qb = blockIdx.x;
  const int tid = threadIdx.x;
  const int w = tid >> 6;
  const int l = tid & 63;
  const int g = l >> 4;
  const int nn = l & 15;

  // ---- Q fragments: A[m=nn][k=c*32+8g+i], metric folded in ----
  const int qrow = qb * 64 + w * 16 + nn;
  const size_t qbase = (size_t)(bh * Nn + qrow);
  f16x8 qf[5];
#pragma unroll
  for (int c = 0; c < 5; ++c) {
    const float* src = (c < 4) ? (qmv + qbase * 128 + c * 32 + 8 * g)
                               : (qs + qbase * 32 + 8 * g);
    float4 a = *(const float4*)src;
    float4 b = *(const float4*)(src + 4);
    float x[8] = {a.x, a.y, a.z, a.w, b.x, b.y, b.z, b.w};
#pragma unroll
    for (int i = 0; i < 8; ++i) {
      float v = x[i];
      if (c < 4) {
        int idx = ((g & 1) << 3) + i;
        v = ((kNegMask >> idx) & 1u) ? -v : v;
      }
      qf[c][i] = (_Float16)v;
    }
  }

  f32x4 accO[10];
#pragma unroll
  for (int j = 0; j < 10; ++j) accO[j] = (f32x4){0.f, 0.f, 0.f, 0.f};
  float M[4] = {-__builtin_inff(), -__builtin_inff(), -__builtin_inff(), -__builtin_inff()};
  float L[4] = {0.f, 0.f, 0.f, 0.f};

  _Float16* pw = p_lds + w * (16 * 40);

  for (int it = 0; it < 32; ++it) {
    const int key0 = it * 32;
    // stage K tile
    for (int s = tid; s < 640; s += 256) {
      int key = s / 20, p = s - key * 20;
      f16x8 val = *(const f16x8*)(Kf + ((size_t)(bh * Nn + key0 + key)) * 160 + p * 8);
      *(f16x8*)&k_lds[key * 168 + p * 8] = val;
    }
    // stage V^T tile
    for (int s = tid; s < 640; s += 256) {
      int d = s >> 2, p = s & 3;
      f16x8 val = *(const f16x8*)(Vt + ((size_t)(bh * 160 + d)) * 1024 + key0 + p * 8);
      *(f16x8*)&v_lds[d * 40 + p * 8] = val;
    }
    __syncthreads();

    // S = Q K^T : two 16x16 key-blocks, K-dim = 160 in 5 chunks
    f32x4 s0 = {0.f, 0.f, 0.f, 0.f}, s1 = {0.f, 0.f, 0.f, 0.f};
#pragma unroll
    for (int c = 0; c < 5; ++c) {
      f16x8 b0 = *(const f16x8*)&k_lds[nn * 168 + c * 32 + 8 * g];
      f16x8 b1 = *(const f16x8*)&k_lds[(16 + nn) * 168 + c * 32 + 8 * g];
      s0 = __builtin_amdgcn_mfma_f32_16x16x32_f16(qf[c], b0, s0, 0, 0, 0);
      s1 = __builtin_amdgcn_mfma_f32_16x16x32_f16(qf[c], b1, s1, 0, 0, 0);
    }

    // online softmax; row m = 4g+r lives in 16 lanes of group g, reg r
    float p0[4], p1[4], fscale[4];
#pragma unroll
    for (int r = 0; r < 4; ++r) {
      float pm = fmaxf(s0[r], s1[r]);
#pragma unroll
      for (int off = 1; off < 16; off <<= 1) pm = fmaxf(pm, __shfl_xor(pm, off, 16));
      float newM = fmaxf(M[r], pm);
      fscale[r] = exp2f((M[r] - newM) * kScaleLog2e);
      M[r] = newM;
      p0[r] = exp2f((s0[r] - newM) * kScaleLog2e);
      p1[r] = exp2f((s1[r] - newM) * kScaleLog2e);
      float t = p0[r] + p1[r];
#pragma unroll
      for (int off = 1; off < 16; off <<= 1) t += __shfl_xor(t, off, 16);
      L[r] = L[r] * fscale[r] + t;
    }
#pragma unroll
    for (int j = 0; j < 10; ++j) {
#pragma unroll
      for (int r = 0; r < 4; ++r) accO[j][r] *= fscale[r];
    }

    // P -> wave-private LDS, re-read as A-frag (row=nn, k=8g+i)
#pragma unroll
    for (int r = 0; r < 4; ++r) {
      pw[(4 * g + r) * 40 + nn] = (_Float16)p0[r];
      pw[(4 * g + r) * 40 + 16 + nn] = (_Float16)p1[r];
    }
    f16x8 pa = *(const f16x8*)&pw[nn * 40 + 8 * g];

    // O += P V : B-frag = V^T rows (d = 16j+nn), keys 8g..8g+7 contiguous
#pragma unroll
    for (int j = 0; j < 10; ++j) {
      f16x8 vb = *(const f16x8*)&v_lds[(16 * j + nn) * 40 + 8 * g];
      accO[j] = __builtin_amdgcn_mfma_f32_16x16x32_f16(pa, vb, accO[j], 0, 0, 0);
    }
    __syncthreads();
  }

  // epilogue: normalize and scatter to (mv | s) output layout
  float rinv[4];
#pragma unroll
  for (int r = 0; r < 4; ++r) rinv[r] = 1.0f / L[r];
  const int row0 = bh * Nn + qb * 64 + w * 16;
#pragma unroll
  for (int j = 0; j < 10; ++j) {
    const int d = 16 * j + nn;
#pragma unroll
    for (int r = 0; r < 4; ++r) {
      const int m = 4 * g + r;
      float val = accO[j][r] * rinv[r];
      if (d < 128)
        out[(size_t)(row0 + m) * 128 + d] = val;
      else
        out[(size_t)kOutMvElems + (size_t)(row0 + m) * 32 + (d - 128)] = val;
    }
  }
}

extern "C" void kernel_launch(void* const* d_in, const int* in_sizes, int n_in,
                              void* d_out, int out_size, void* d_ws, size_t ws_size,
                              hipStream_t stream) {
  const float* qmv = (const float*)d_in[0];
  const float* kmv = (const float*)d_in[1];
  const float* vmv = (const float*)d_in[2];
  const float* qs = (const float*)d_in[3];
  const float* ks = (const float*)d_in[4];
  const float* vs = (const float*)d_in[5];
  float* out = (float*)d_out;

  _Float16* Kf = (_Float16*)d_ws;                       // 64*1024*160 f16 = 20.97 MB
  _Float16* Vt = Kf + (size_t)BHn * Nn * 160;           // 64*160*1024 f16 = 20.97 MB

  pack_k_kernel<<<dim3((BHn * Nn * 20) / 256), dim3(256), 0, stream>>>(kmv, ks, Kf);
  pack_vt_kernel<<<dim3(16, BHn), dim3(256), 0, stream>>>(vmv, vs, Vt);
  geo_attn_kernel<<<dim3(16, BHn), dim3(256), 0, stream>>>(qmv, qs, Kf, Vt, out);
}

// Round 2
// 138.344 us; speedup vs baseline: 1.7367x; 1.7367x over previous
//
#include <hip/hip_runtime.h>

typedef __attribute__((ext_vector_type(8))) _Float16 f16x8;
typedef __attribute__((ext_vector_type(4))) _Float16 f16x4;
typedef __attribute__((ext_vector_type(4))) float f32x4;

#define BHn 64
#define Nn 1024

static constexpr int kOutMvElems = 8 * 8 * 1024 * 128;      // 8388608
static constexpr float kScaleLog2e = 0.11405506f;           // log2(e)/sqrt(160)
static constexpr unsigned kNegMask = 0xBF1Cu;               // BLADE_METRIC<0 bit i

// ---------------- pack K: f32 (mv|s) -> f16 [bh][key][160] ----------------
__global__ __launch_bounds__(256) void pack_k_kernel(const float* __restrict__ kmv,
                                                     const float* __restrict__ ks,
                                                     _Float16* __restrict__ Kf) {
  int t = blockIdx.x * 256 + threadIdx.x;  // 16B segment id
  const int total = BHn * Nn * 20;
  if (t >= total) return;
  int row = t / 20, s = t - row * 20;
  const float* src = (s < 16) ? (kmv + (size_t)row * 128 + s * 8)
                              : (ks + (size_t)row * 32 + (s - 16) * 8);
  float4 a = *(const float4*)src;
  float4 b = *(const float4*)(src + 4);
  f16x8 h;
  h[0] = (_Float16)a.x; h[1] = (_Float16)a.y; h[2] = (_Float16)a.z; h[3] = (_Float16)a.w;
  h[4] = (_Float16)b.x; h[5] = (_Float16)b.y; h[6] = (_Float16)b.z; h[7] = (_Float16)b.w;
  *(f16x8*)(Kf + (size_t)row * 160 + s * 8) = h;
}

// ---------------- pack V transposed: f32 [bh][key][160] -> f16 [bh][d][1024] ----------------
__global__ __launch_bounds__(256) void pack_vt_kernel(const float* __restrict__ vmv,
                                                      const float* __restrict__ vs,
                                                      _Float16* __restrict__ Vt) {
  __shared__ _Float16 tile[160][72];
  const int bh = blockIdx.y;
  const int kt = blockIdx.x;  // 16 tiles of 64 keys
  const int tid = threadIdx.x;
  for (int s = tid; s < 64 * 40; s += 256) {
    int key = s / 40, p = s - key * 40;
    int row = bh * Nn + kt * 64 + key;
    const float* src = (p < 32) ? (vmv + (size_t)row * 128 + p * 4)
                                : (vs + (size_t)row * 32 + (p - 32) * 4);
    float4 v = *(const float4*)src;
    int d = p * 4;
    tile[d + 0][key] = (_Float16)v.x;
    tile[d + 1][key] = (_Float16)v.y;
    tile[d + 2][key] = (_Float16)v.z;
    tile[d + 3][key] = (_Float16)v.w;
  }
  __syncthreads();
  for (int s = tid; s < 160 * 8; s += 256) {
    int d = s >> 3, p = s & 7;
    f16x8 h = *(const f16x8*)&tile[d][p * 8];
    *(f16x8*)(Vt + ((size_t)(bh * 160 + d)) * 1024 + kt * 64 + p * 8) = h;
  }
}

// ---------------- flash attention, swapped-QK^T, 4 waves x 32 rows ----------------
// grid: 512 blocks (XCD-swizzled -> (qb, bh)); 256 threads = 4 waves.
__global__ __launch_bounds__(256, 2) void geo_attn_kernel(const float* __restrict__ qmv,
                                                          const float* __restrict__ qs,
                                                          const _Float16* __restrict__ Kf,
                                                          const _Float16* __restrict__ Vt,
                                                          float* __restrict__ out) {
  __shared__ _Float16 k_lds[64 * 192];    // 64 keys x 160 (stride 192 for bijective swizzle)
  __shared__ _Float16 v_lds[160 * 64];    // 160 d x 64 keys
  __shared__ _Float16 p_lds[4 * 32 * 72]; // per-wave P scratch, stride 72

  // XCD swizzle: each XCD gets 8 whole bh's (all 8 q-blocks each)
  const int b = blockIdx.x;
  const int sw = (b & 7) * 64 + (b >> 3);
  const int qb = sw & 7;
  const int bh = sw >> 3;

  const int tid = threadIdx.x;
  const int w = tid >> 6;
  const int l = tid & 63;
  const int g = l >> 4;
  const int nn = l & 15;
  const int swz = (nn & 7) << 3;

  // ---- Q fragments (B-frag): lane holds Q[q=nn(+16)][c*32+8g+i], metric*log2e/sqrt(d) folded ----
  f16x8 qf[2][5];
#pragma unroll
  for (int q2 = 0; q2 < 2; ++q2) {
    const size_t qbase = (size_t)(bh * Nn + qb * 128 + w * 32 + q2 * 16 + nn);
#pragma unroll
    for (int c = 0; c < 5; ++c) {
      const float* src = (c < 4) ? (qmv + qbase * 128 + c * 32 + 8 * g)
                                 : (qs + qbase * 32 + 8 * g);
      float4 a = *(const float4*)src;
      float4 bb = *(const float4*)(src + 4);
      float x[8] = {a.x, a.y, a.z, a.w, bb.x, bb.y, bb.z, bb.w};
#pragma unroll
      for (int i = 0; i < 8; ++i) {
        float v = x[i] * kScaleLog2e;
        if (c < 4) {
          int idx = ((g & 1) << 3) + i;
          v = ((kNegMask >> idx) & 1u) ? -v : v;
        }
        qf[q2][c][i] = (_Float16)v;
      }
    }
  }

  f32x4 acc[2][10];
#pragma unroll
  for (int q2 = 0; q2 < 2; ++q2)
#pragma unroll
    for (int j = 0; j < 10; ++j) acc[q2][j] = (f32x4){0.f, 0.f, 0.f, 0.f};
  float Ma = -3.0e38f, Mb = -3.0e38f, La = 0.f, Lb = 0.f;

  _Float16* pP = p_lds + w * (32 * 72);
  const _Float16* kgbase = Kf + (size_t)(bh * Nn) * 160;
  const _Float16* vgbase = Vt + (size_t)bh * 160 * Nn;

  f16x8 stK[5], stV[5];
  auto stage_load = [&](int key0) {
#pragma unroll
    for (int i = 0; i < 5; ++i) {
      int s = tid + 256 * i;
      stK[i] = *(const f16x8*)(kgbase + (size_t)key0 * 160 + s * 8);
    }
#pragma unroll
    for (int i = 0; i < 5; ++i) {
      int s = tid + 256 * i;
      int d = s >> 3, cs = s & 7;
      stV[i] = *(const f16x8*)(vgbase + (size_t)d * Nn + key0 + cs * 8);
    }
  };
  auto stage_write = [&]() {
#pragma unroll
    for (int i = 0; i < 5; ++i) {
      int s = tid + 256 * i;
      int key = s / 20, p = s - key * 20;
      int idx = (key * 192 + p * 8) ^ ((key & 7) << 3);
      *(f16x8*)&k_lds[idx] = stK[i];
    }
#pragma unroll
    for (int i = 0; i < 5; ++i) {
      int s = tid + 256 * i;
      int d = s >> 3, cs = s & 7;
      int idx = (d * 64 + cs * 8) ^ ((d & 7) << 3);
      *(f16x8*)&v_lds[idx] = stV[i];
    }
  };

  stage_load(0);

  for (int it = 0; it < 16; ++it) {
    __syncthreads();          // all waves done reading previous tile
    stage_write();
    __syncthreads();          // tile ready

    // ---- S^T = K Q^T : lane (nn,g) gets scores of q-row nn, keys 16kb+4g+r ----
    f32x4 sa[4], sb[4];
#pragma unroll
    for (int kb = 0; kb < 4; ++kb) {
      sa[kb] = (f32x4){0.f, 0.f, 0.f, 0.f};
      sb[kb] = (f32x4){0.f, 0.f, 0.f, 0.f};
    }
#pragma unroll
    for (int c = 0; c < 5; ++c) {
      f16x8 kf[4];
#pragma unroll
      for (int kb = 0; kb < 4; ++kb)
        kf[kb] = *(const f16x8*)&k_lds[((16 * kb + nn) * 192 + c * 32 + 8 * g) ^ swz];
#pragma unroll
      for (int kb = 0; kb < 4; ++kb) {
        sa[kb] = __builtin_amdgcn_mfma_f32_16x16x32_f16(kf[kb], qf[0][c], sa[kb], 0, 0, 0);
        sb[kb] = __builtin_amdgcn_mfma_f32_16x16x32_f16(kf[kb], qf[1][c], sb[kb], 0, 0, 0);
      }
    }

    if (it < 15) stage_load((it + 1) * 64);  // prefetch: latency hides under softmax+PV

    // ---- online softmax (scores already in log2 domain) ----
    float pma = fmaxf(fmaxf(fmaxf(fmaxf(sa[0][0], sa[0][1]), fmaxf(sa[0][2], sa[0][3])),
                            fmaxf(fmaxf(sa[1][0], sa[1][1]), fmaxf(sa[1][2], sa[1][3]))),
                      fmaxf(fmaxf(fmaxf(sa[2][0], sa[2][1]), fmaxf(sa[2][2], sa[2][3])),
                            fmaxf(fmaxf(sa[3][0], sa[3][1]), fmaxf(sa[3][2], sa[3][3]))));
    float pmb = fmaxf(fmaxf(fmaxf(fmaxf(sb[0][0], sb[0][1]), fmaxf(sb[0][2], sb[0][3])),
                            fmaxf(fmaxf(sb[1][0], sb[1][1]), fmaxf(sb[1][2], sb[1][3]))),
                      fmaxf(fmaxf(fmaxf(sb[2][0], sb[2][1]), fmaxf(sb[2][2], sb[2][3])),
                            fmaxf(fmaxf(sb[3][0], sb[3][1]), fmaxf(sb[3][2], sb[3][3]))));
    pma = fmaxf(pma, __shfl_xor(pma, 16));
    pma = fmaxf(pma, __shfl_xor(pma, 32));
    pmb = fmaxf(pmb, __shfl_xor(pmb, 16));
    pmb = fmaxf(pmb, __shfl_xor(pmb, 32));

    float fsa_l = 1.f, fsb_l = 1.f;
    bool defer = (pma - Ma <= 8.f) && (pmb - Mb <= 8.f);
    if (!__all((int)defer)) {           // T13 defer-rescale
      float nMa = fmaxf(Ma, pma); fsa_l = exp2f(Ma - nMa); Ma = nMa;
      float nMb = fmaxf(Mb, pmb); fsb_l = exp2f(Mb - nMb); Mb = nMb;
      float fa[4], fb[4];
#pragma unroll
      for (int r = 0; r < 4; ++r) {
        fa[r] = __shfl(fsa_l, 4 * g + r, 16);
        fb[r] = __shfl(fsb_l, 4 * g + r, 16);
      }
#pragma unroll
      for (int j = 0; j < 10; ++j)
#pragma unroll
        for (int r = 0; r < 4; ++r) {
          acc[0][j][r] *= fa[r];
          acc[1][j][r] *= fb[r];
        }
    }

    float rsa = 0.f, rsb = 0.f;
    f16x4 pka[4], pkb[4];
#pragma unroll
    for (int kb = 0; kb < 4; ++kb)
#pragma unroll
      for (int r = 0; r < 4; ++r) {
        float pa_ = exp2f(sa[kb][r] - Ma);
        float pb_ = exp2f(sb[kb][r] - Mb);
        rsa += pa_;
        rsb += pb_;
        pka[kb][r] = (_Float16)pa_;
        pkb[kb][r] = (_Float16)pb_;
      }
    rsa += __shfl_xor(rsa, 16); rsa += __shfl_xor(rsa, 32);
    rsb += __shfl_xor(rsb, 16); rsb += __shfl_xor(rsb, 32);
    La = La * fsa_l + rsa;
    Lb = Lb * fsb_l + rsb;

    // ---- P -> wave-private LDS (packed b64 writes), re-read as A-frags ----
#pragma unroll
    for (int kb = 0; kb < 4; ++kb) {
      *(f16x4*)&pP[nn * 72 + 16 * kb + 4 * g] = pka[kb];
      *(f16x4*)&pP[(16 + nn) * 72 + 16 * kb + 4 * g] = pkb[kb];
    }

    // ---- O += P V ----
#pragma unroll
    for (int ch = 0; ch < 2; ++ch) {
      f16x8 pa = *(const f16x8*)&pP[nn * 72 + ch * 32 + 8 * g];
      f16x8 pb = *(const f16x8*)&pP[(16 + nn) * 72 + ch * 32 + 8 * g];
#pragma unroll
      for (int j = 0; j < 10; ++j) {
        f16x8 vb = *(const f16x8*)&v_lds[((16 * j + nn) * 64 + ch * 32 + 8 * g) ^ swz];
        acc[0][j] = __builtin_amdgcn_mfma_f32_16x16x32_f16(pa, vb, acc[0][j], 0, 0, 0);
        acc[1][j] = __builtin_amdgcn_mfma_f32_16x16x32_f16(pb, vb, acc[1][j], 0, 0, 0);
      }
    }
  }

  // ---- epilogue ----
  float ria = 1.f / La, rib = 1.f / Lb;
  float ra[4], rb_[4];
#pragma unroll
  for (int r = 0; r < 4; ++r) {
    ra[r] = __shfl(ria, 4 * g + r, 16);
    rb_[r] = __shfl(rib, 4 * g + r, 16);
  }
  const int row0 = bh * Nn + qb * 128 + w * 32;
#pragma unroll
  for (int j = 0; j < 10; ++j) {
    const int d = 16 * j + nn;
#pragma unroll
    for (int r = 0; r < 4; ++r) {
      float v0 = acc[0][j][r] * ra[r];
      float v1 = acc[1][j][r] * rb_[r];
      const int r0 = row0 + 4 * g + r;
      const int r1 = row0 + 16 + 4 * g + r;
      if (d < 128) {
        out[(size_t)r0 * 128 + d] = v0;
        out[(size_t)r1 * 128 + d] = v1;
      } else {
        out[(size_t)kOutMvElems + (size_t)r0 * 32 + (d - 128)] = v0;
        out[(size_t)kOutMvElems + (size_t)r1 * 32 + (d - 128)] = v1;
      }
    }
  }
}

extern "C" void kernel_launch(void* const* d_in, const int* in_sizes, int n_in,
                              void* d_out, int out_size, void* d_ws, size_t ws_size,
                              hipStream_t stream) {
  const float* qmv = (const float*)d_in[0];
  const float* kmv = (const float*)d_in[1];
  const float* vmv = (const float*)d_in[2];
  const float* qs = (const float*)d_in[3];
  const float* ks = (const float*)d_in[4];
  const float* vs = (const float*)d_in[5];
  float* out = (float*)d_out;

  _Float16* Kf = (_Float16*)d_ws;                       // 64*1024*160 f16
  _Float16* Vt = Kf + (size_t)BHn * Nn * 160;           // 64*160*1024 f16

  pack_k_kernel<<<dim3((BHn * Nn * 20) / 256), dim3(256), 0, stream>>>(kmv, ks, Kf);
  pack_vt_kernel<<<dim3(16, BHn), dim3(256), 0, stream>>>(vmv, vs, Vt);
  geo_attn_kernel<<<dim3(512), dim3(256), 0, stream>>>(qmv, qs, Kf, Vt, out);
}

// Round 3
// 94.141 us; speedup vs baseline: 2.5522x; 1.4695x over previous
//
#include <hip/hip_runtime.h>

typedef __attribute__((ext_vector_type(8))) _Float16 f16x8;
typedef __attribute__((ext_vector_type(4))) _Float16 f16x4;
typedef __attribute__((ext_vector_type(4))) float f32x4;

#define BHn 64
#define Nn 1024

static constexpr int kOutMvElems = 8 * 8 * 1024 * 128;      // 8388608
static constexpr float kScaleLog2e = 0.11405506f;           // log2(e)/sqrt(160)
static constexpr unsigned kNegMask = 0xBF1Cu;               // BLADE_METRIC<0 bit i

// ---------------- pack K: f32 (mv|s) -> f16 [bh][key][160] ----------------
__global__ __launch_bounds__(256) void pack_k_kernel(const float* __restrict__ kmv,
                                                     const float* __restrict__ ks,
                                                     _Float16* __restrict__ Kf) {
  int t = blockIdx.x * 256 + threadIdx.x;  // 16B segment id
  const int total = BHn * Nn * 20;
  if (t >= total) return;
  int row = t / 20, s = t - row * 20;
  const float* src = (s < 16) ? (kmv + (size_t)row * 128 + s * 8)
                              : (ks + (size_t)row * 32 + (s - 16) * 8);
  float4 a = *(const float4*)src;
  float4 b = *(const float4*)(src + 4);
  f16x8 h;
  h[0] = (_Float16)a.x; h[1] = (_Float16)a.y; h[2] = (_Float16)a.z; h[3] = (_Float16)a.w;
  h[4] = (_Float16)b.x; h[5] = (_Float16)b.y; h[6] = (_Float16)b.z; h[7] = (_Float16)b.w;
  *(f16x8*)(Kf + (size_t)row * 160 + s * 8) = h;
}

// ---- pack V transposed + slot-permuted: f32 [bh][key][160] -> f16 [bh][d][1024] ----
// Column order within each 32-key chunk is sigma(slot): slot 8g+i -> key 4g+i (i<4),
// 16+4g+(i-4) (i>=4). This makes the PV A-fragment lane-local (zero-shuffle P).
__global__ __launch_bounds__(256) void pack_vt_kernel(const float* __restrict__ vmv,
                                                      const float* __restrict__ vs,
                                                      _Float16* __restrict__ Vt) {
  __shared__ _Float16 tile[160][72];
  const int bh = blockIdx.y;
  const int kt = blockIdx.x;  // 16 tiles of 64 keys
  const int tid = threadIdx.x;
  for (int s = tid; s < 64 * 40; s += 256) {
    int key = s / 40, p = s - key * 40;
    int row = bh * Nn + kt * 64 + key;
    const float* src = (p < 32) ? (vmv + (size_t)row * 128 + p * 4)
                                : (vs + (size_t)row * 32 + (p - 32) * 4);
    float4 v = *(const float4*)src;
    int d = p * 4;
    tile[d + 0][key] = (_Float16)v.x;
    tile[d + 1][key] = (_Float16)v.y;
    tile[d + 2][key] = (_Float16)v.z;
    tile[d + 3][key] = (_Float16)v.w;
  }
  __syncthreads();
  for (int s = tid; s < 160 * 8; s += 256) {
    int d = s >> 3, o = s & 7;                 // o = output octet within 64 cols
    int c32 = (o >> 2) * 32;                   // 32-key chunk base
    int g4 = (o & 3) * 4;
    f16x4 lo = *(const f16x4*)&tile[d][c32 + g4];        // keys 4g..4g+3
    f16x4 hi = *(const f16x4*)&tile[d][c32 + 16 + g4];   // keys 16+4g..16+4g+3
    f16x8 h;
    h[0] = lo[0]; h[1] = lo[1]; h[2] = lo[2]; h[3] = lo[3];
    h[4] = hi[0]; h[5] = hi[1]; h[6] = hi[2]; h[7] = hi[3];
    *(f16x8*)(Vt + ((size_t)(bh * 160 + d)) * 1024 + kt * 64 + o * 8) = h;
  }
}

// ---------------- flash attention: 8 waves x 32 rows, dbuf LDS, 1 barrier/iter ----------------
// grid: 256 blocks (XCD-swizzled -> (qb, bh)); 512 threads = 8 waves.
__global__ __launch_bounds__(512, 2) void geo_attn_kernel(const float* __restrict__ qmv,
                                                          const float* __restrict__ qs,
                                                          const _Float16* __restrict__ Kf,
                                                          const _Float16* __restrict__ Vt,
                                                          float* __restrict__ out) {
  __shared__ _Float16 k_lds[2][64 * 192];   // 64 keys x 160 (stride 192), double-buffered
  __shared__ _Float16 v_lds[2][160 * 64];   // 160 d x 64 slots, double-buffered

  // XCD swizzle: 256 blocks, XCD x gets bh 8x..8x+7 (all 4 q-blocks each)
  const int b = blockIdx.x;
  const int sw = (b & 7) * 32 + (b >> 3);
  const int qb = sw & 3;
  const int bh = sw >> 2;

  const int tid = threadIdx.x;
  const int w = tid >> 6;
  const int l = tid & 63;
  const int g = l >> 4;
  const int nn = l & 15;
  const int swz = (nn & 7) << 3;

  // ---- Q fragments (B-frag): lane holds Q[q=nn(+16)][c*32+8g+i], metric*log2e/sqrt(d) folded ----
  f16x8 qf[2][5];
#pragma unroll
  for (int q2 = 0; q2 < 2; ++q2) {
    const size_t qbase = (size_t)(bh * Nn + qb * 256 + w * 32 + q2 * 16 + nn);
#pragma unroll
    for (int c = 0; c < 5; ++c) {
      const float* src = (c < 4) ? (qmv + qbase * 128 + c * 32 + 8 * g)
                                 : (qs + qbase * 32 + 8 * g);
      float4 a = *(const float4*)src;
      float4 bb = *(const float4*)(src + 4);
      float x[8] = {a.x, a.y, a.z, a.w, bb.x, bb.y, bb.z, bb.w};
#pragma unroll
      for (int i = 0; i < 8; ++i) {
        float v = x[i] * kScaleLog2e;
        if (c < 4) {
          int idx = ((g & 1) << 3) + i;
          v = ((kNegMask >> idx) & 1u) ? -v : v;
        }
        qf[q2][c][i] = (_Float16)v;
      }
    }
  }

  f32x4 acc[2][10];
#pragma unroll
  for (int q2 = 0; q2 < 2; ++q2)
#pragma unroll
    for (int j = 0; j < 10; ++j) acc[q2][j] = (f32x4){0.f, 0.f, 0.f, 0.f};
  float Ma = -3.0e38f, Mb = -3.0e38f, La = 0.f, Lb = 0.f;

  const _Float16* kgbase = Kf + (size_t)(bh * Nn) * 160;
  const _Float16* vgbase = Vt + (size_t)bh * 160 * Nn;

  // combined K+V staging: 2560 16B segments / 512 threads = 5 each
  f16x8 st[5];
  auto stage_load = [&](int key0) {
#pragma unroll
    for (int i = 0; i < 5; ++i) {
      int s = tid + 512 * i;
      if (s < 1280) {
        st[i] = *(const f16x8*)(kgbase + (size_t)key0 * 160 + s * 8);
      } else {
        int s2 = s - 1280;
        int d = s2 >> 3, cs = s2 & 7;
        st[i] = *(const f16x8*)(vgbase + (size_t)d * Nn + key0 + cs * 8);
      }
    }
  };
  auto stage_write = [&](int buf) {
#pragma unroll
    for (int i = 0; i < 5; ++i) {
      int s = tid + 512 * i;
      if (s < 1280) {
        int key = s / 20, p = s - key * 20;
        int idx = (key * 192 + p * 8) ^ ((key & 7) << 3);
        *(f16x8*)&k_lds[buf][idx] = st[i];
      } else {
        int s2 = s - 1280;
        int d = s2 >> 3, cs = s2 & 7;
        int idx = (d * 64 + cs * 8) ^ ((d & 7) << 3);
        *(f16x8*)&v_lds[buf][idx] = st[i];
      }
    }
  };

  stage_load(0);
  stage_write(0);
  __syncthreads();

  for (int it = 0; it < 16; ++it) {
    const int cur = it & 1;
    if (it < 15) stage_load((it + 1) * 64);  // T14: issue early, write after compute

    // ---- S^T = K Q^T : lane (g,nn) -> scores of q-row nn, keys 16kb+4g+r ----
    f32x4 sa[4], sb[4];
#pragma unroll
    for (int kb = 0; kb < 4; ++kb) {
      sa[kb] = (f32x4){0.f, 0.f, 0.f, 0.f};
      sb[kb] = (f32x4){0.f, 0.f, 0.f, 0.f};
    }
    __builtin_amdgcn_s_setprio(1);
#pragma unroll
    for (int c = 0; c < 5; ++c) {
      f16x8 kf[4];
#pragma unroll
      for (int kb = 0; kb < 4; ++kb)
        kf[kb] = *(const f16x8*)&k_lds[cur][((16 * kb + nn) * 192 + c * 32 + 8 * g) ^ swz];
#pragma unroll
      for (int kb = 0; kb < 4; ++kb) {
        sa[kb] = __builtin_amdgcn_mfma_f32_16x16x32_f16(kf[kb], qf[0][c], sa[kb], 0, 0, 0);
        sb[kb] = __builtin_amdgcn_mfma_f32_16x16x32_f16(kf[kb], qf[1][c], sb[kb], 0, 0, 0);
      }
    }
    __builtin_amdgcn_s_setprio(0);

    // ---- online softmax (log2 domain) ----
    float pma = fmaxf(fmaxf(fmaxf(fmaxf(sa[0][0], sa[0][1]), fmaxf(sa[0][2], sa[0][3])),
                            fmaxf(fmaxf(sa[1][0], sa[1][1]), fmaxf(sa[1][2], sa[1][3]))),
                      fmaxf(fmaxf(fmaxf(sa[2][0], sa[2][1]), fmaxf(sa[2][2], sa[2][3])),
                            fmaxf(fmaxf(sa[3][0], sa[3][1]), fmaxf(sa[3][2], sa[3][3]))));
    float pmb = fmaxf(fmaxf(fmaxf(fmaxf(sb[0][0], sb[0][1]), fmaxf(sb[0][2], sb[0][3])),
                            fmaxf(fmaxf(sb[1][0], sb[1][1]), fmaxf(sb[1][2], sb[1][3]))),
                      fmaxf(fmaxf(fmaxf(sb[2][0], sb[2][1]), fmaxf(sb[2][2], sb[2][3])),
                            fmaxf(fmaxf(sb[3][0], sb[3][1]), fmaxf(sb[3][2], sb[3][3]))));
    pma = fmaxf(pma, __shfl_xor(pma, 16));
    pma = fmaxf(pma, __shfl_xor(pma, 32));
    pmb = fmaxf(pmb, __shfl_xor(pmb, 16));
    pmb = fmaxf(pmb, __shfl_xor(pmb, 32));

    float fsa_l = 1.f, fsb_l = 1.f;
    bool defer = (pma - Ma <= 8.f) && (pmb - Mb <= 8.f);
    if (!__all((int)defer)) {           // T13 defer-rescale
      float nMa = fmaxf(Ma, pma); fsa_l = exp2f(Ma - nMa); Ma = nMa;
      float nMb = fmaxf(Mb, pmb); fsb_l = exp2f(Mb - nMb); Mb = nMb;
      float fa[4], fb[4];
#pragma unroll
      for (int r = 0; r < 4; ++r) {
        fa[r] = __shfl(fsa_l, 4 * g + r, 16);
        fb[r] = __shfl(fsb_l, 4 * g + r, 16);
      }
#pragma unroll
      for (int j = 0; j < 10; ++j)
#pragma unroll
        for (int r = 0; r < 4; ++r) {
          acc[0][j][r] *= fa[r];
          acc[1][j][r] *= fb[r];
        }
    }

    // ---- P in-register (zero-shuffle, sigma slot order) ----
    float rsa = 0.f, rsb = 0.f;
    f16x8 paf[2], pbf[2];
#pragma unroll
    for (int kb = 0; kb < 4; ++kb) {
      const int ch = kb >> 1, off = (kb & 1) * 4;
#pragma unroll
      for (int r = 0; r < 4; ++r) {
        float pa_ = exp2f(sa[kb][r] - Ma);
        float pb_ = exp2f(sb[kb][r] - Mb);
        rsa += pa_; rsb += pb_;
        paf[ch][off + r] = (_Float16)pa_;
        pbf[ch][off + r] = (_Float16)pb_;
      }
    }
    rsa += __shfl_xor(rsa, 16); rsa += __shfl_xor(rsa, 32);
    rsb += __shfl_xor(rsb, 16); rsb += __shfl_xor(rsb, 32);
    La = La * fsa_l + rsa;
    Lb = Lb * fsb_l + rsb;

    // ---- O += P V (V columns pre-permuted by sigma at pack time) ----
    __builtin_amdgcn_s_setprio(1);
#pragma unroll
    for (int ch = 0; ch < 2; ++ch) {
#pragma unroll
      for (int j = 0; j < 10; ++j) {
        f16x8 vb = *(const f16x8*)&v_lds[cur][((16 * j + nn) * 64 + ch * 32 + 8 * g) ^ swz];
        acc[0][j] = __builtin_amdgcn_mfma_f32_16x16x32_f16(paf[ch], vb, acc[0][j], 0, 0, 0);
        acc[1][j] = __builtin_amdgcn_mfma_f32_16x16x32_f16(pbf[ch], vb, acc[1][j], 0, 0, 0);
      }
    }
    __builtin_amdgcn_s_setprio(0);

    if (it < 15) stage_write(cur ^ 1);  // loads have been in flight across QK+softmax+PV
    __syncthreads();
  }

  // ---- epilogue ----
  float ria = 1.f / La, rib = 1.f / Lb;
  float ra[4], rb_[4];
#pragma unroll
  for (int r = 0; r < 4; ++r) {
    ra[r] = __shfl(ria, 4 * g + r, 16);
    rb_[r] = __shfl(rib, 4 * g + r, 16);
  }
  const int row0 = bh * Nn + qb * 256 + w * 32;
#pragma unroll
  for (int j = 0; j < 10; ++j) {
    const int d = 16 * j + nn;
#pragma unroll
    for (int r = 0; r < 4; ++r) {
      float v0 = acc[0][j][r] * ra[r];
      float v1 = acc[1][j][r] * rb_[r];
      const int r0 = row0 + 4 * g + r;
      const int r1 = row0 + 16 + 4 * g + r;
      if (d < 128) {
        out[(size_t)r0 * 128 + d] = v0;
        out[(size_t)r1 * 128 + d] = v1;
      } else {
        out[(size_t)kOutMvElems + (size_t)r0 * 32 + (d - 128)] = v0;
        out[(size_t)kOutMvElems + (size_t)r1 * 32 + (d - 128)] = v1;
      }
    }
  }
}

extern "C" void kernel_launch(void* const* d_in, const int* in_sizes, int n_in,
                              void* d_out, int out_size, void* d_ws, size_t ws_size,
                              hipStream_t stream) {
  const float* qmv = (const float*)d_in[0];
  const float* kmv = (const float*)d_in[1];
  const float* vmv = (const float*)d_in[2];
  const float* qs = (const float*)d_in[3];
  const float* ks = (const float*)d_in[4];
  const float* vs = (const float*)d_in[5];
  float* out = (float*)d_out;

  _Float16* Kf = (_Float16*)d_ws;                       // 64*1024*160 f16
  _Float16* Vt = Kf + (size_t)BHn * Nn * 160;           // 64*160*1024 f16 (sigma-permuted)

  pack_k_kernel<<<dim3((BHn * Nn * 20) / 256), dim3(256), 0, stream>>>(kmv, ks, Kf);
  pack_vt_kernel<<<dim3(16, BHn), dim3(256), 0, stream>>>(vmv, vs, Vt);
  geo_attn_kernel<<<dim3(256), dim3(512), 0, stream>>>(qmv, qs, Kf, Vt, out);
}